// Round 1
// 523.822 us; speedup vs baseline: 1.0115x; 1.0115x over previous
//
#include <hip/hip_runtime.h>
#include <stdint.h>

// Contrast loss, fully fused on-GPU:
//  0) prep: pack pos -> bits P[N][N/32]; cast z/W to fp8 e4m3 (one launch)
//  1) proj_fused: per 64-row block:  h = ELU(z @ W1^T + b1) kept in LDS (fp8),
//     zp = h @ W2^T + b2 kept in REGISTERS, row-norm -> zn fp8 (one launch).
//     Eliminates the h and zp global round trips and the separate norm kernel.
//  2) sim: S = zn_mp @ zn_sc^T via MX-fp8 MFMA (BK=128, LDS-staged,
//     XOR-swizzled); e = exp(S); masked row/col partials -> unique slots
//  3) two-stage reduction -> scalar loss

#define NN 8192
#define HH 512
#define TAUF 0.8f
#define EPSF 1e-8f
#define NW (NN / 32)

typedef __attribute__((ext_vector_type(4))) float f32x4;
typedef __attribute__((ext_vector_type(2))) int i32x2;
typedef __attribute__((ext_vector_type(4))) int i32x4;
typedef __attribute__((ext_vector_type(8))) int i32x8;
typedef unsigned short u16;
typedef unsigned int u32;
typedef uint8_t u8;

typedef __attribute__((address_space(1))) void GV;
typedef __attribute__((address_space(3))) void LV;

__device__ __forceinline__ void g2l16(const void* g, void* l) {
  __builtin_amdgcn_global_load_lds((const GV*)g, (LV*)l, 16, 0, 0);
}

// software f32 -> fp8 e4m3fn (OCP), RNE. |x| < 448 in our use.
__device__ __forceinline__ u32 f2fp8(float x) {
  u32 u = __builtin_bit_cast(u32, x);
  u32 s = (u >> 31) << 7;
  float a = fabsf(x);
  if (a >= 0.015625f) {
    u32 b = __builtin_bit_cast(u32, a);
    b += 0x7FFFFu + ((b >> 20) & 1u);
    u32 e = (b >> 23) - 127u + 7u;
    u32 m = (b >> 20) & 7u;
    return s | (e << 3) | m;
  } else {
    int m = (int)rintf(a * 512.0f);
    return s | (u32)m;
  }
}

__device__ __forceinline__ void cast8f8(const float* __restrict__ in, u8* __restrict__ out, int i) {
  f32x4 a = *(const f32x4*)(in + i);
  f32x4 b = *(const f32x4*)(in + i + 4);
  i32x2 v;
  v.x = (int)(f2fp8(a.x) | (f2fp8(a.y) << 8) | (f2fp8(a.z) << 16) | (f2fp8(a.w) << 24));
  v.y = (int)(f2fp8(b.x) | (f2fp8(b.y) << 8) | (f2fp8(b.z) << 16) | (f2fp8(b.w) << 24));
  *(i32x2*)(out + i) = v;
}

// ---------------- merged prep: pack pos + all fp8 casts ----------------
__global__ __launch_bounds__(256)
void prep_kernel(const int* __restrict__ pos, u32* __restrict__ P,
                 const float* __restrict__ z_mp, u8* __restrict__ zbA,
                 const float* __restrict__ z_sc, u8* __restrict__ zbB,
                 const float* __restrict__ W1, u8* __restrict__ W1b,
                 const float* __restrict__ W2, u8* __restrict__ W2b) {
  int b = blockIdx.x, tid = threadIdx.x;
  if (b < 8192) {
    int gid = b * 256 + tid;
    const int* src = pos + (size_t)gid * 32;
    u32 w = 0;
#pragma unroll
    for (int c = 0; c < 8; ++c) {
      i32x4 p = *(const i32x4*)(src + c * 4);
      w |= ((u32)p.x & 1u) << (c * 4);
      w |= ((u32)p.y & 1u) << (c * 4 + 1);
      w |= ((u32)p.z & 1u) << (c * 4 + 2);
      w |= ((u32)p.w & 1u) << (c * 4 + 3);
    }
    P[gid] = w;
  } else if (b < 10240) {
    cast8f8(z_mp, zbA, ((b - 8192) * 256 + tid) * 8);
  } else if (b < 12288) {
    cast8f8(z_sc, zbB, ((b - 10240) * 256 + tid) * 8);
  } else if (b < 12416) {
    cast8f8(W1, W1b, ((b - 12288) * 256 + tid) * 8);
  } else {
    cast8f8(W2, W2b, ((b - 12416) * 256 + tid) * 8);
  }
}

// ---------------- fused projection: z -> h(LDS) -> zp(regs) -> zn (fp8) ----------------
// 256 blocks (128 per input), 64 rows each, 4 waves. Wave w owns output cols
// [w*128, w*128+128). acc[4][8] f32x4 = 128 VGPR/thread in phase 2.
__global__ __launch_bounds__(256, 1)
void proj_fused(const u8* __restrict__ zbA, const u8* __restrict__ zbB,
                const u8* __restrict__ W1b, const float* __restrict__ b1,
                const u8* __restrict__ W2b, const float* __restrict__ b2,
                u8* __restrict__ znA, u8* __restrict__ znB) {
  __shared__ __align__(16) u8 Az[64 * 512];   // 32 KB: z fp8 (swz); reused for zn staging
  __shared__ __align__(16) u8 Hs[64 * 512];   // 32 KB: h fp8 (swz)
  __shared__ __align__(16) u8 Ws[512 * 128];  // 64 KB: W k-window, rows swizzled
  __shared__ float ssqL[4][64];
  __shared__ float invL[64];

  const int tid = threadIdx.x;
  const int lane = tid & 63, w = tid >> 6;
  const int lo = lane & 15, quad = lane >> 4;
  const int b = blockIdx.x;
  const bool isA = b < 128;
  const int m0 = (b & 127) * 64;
  const u8* zb = isA ? zbA : zbB;
  u8* zn = isA ? znA : znB;
  const float nscale = isA ? (1.0f / TAUF) : 1.0f;

  char* AzB = (char*)Az;
  char* HsB = (char*)Hs;
  char* WsB = (char*)Ws;

  // ---- stage Az (64 z-rows, fp8, per-128B-window XOR swizzle) + W1 window 0 ----
  {
    const int ls = lane >> 5;    // row within 1KB call (2 rows/call)
    const int ch = lane & 31;    // 16B chunk within 512B row
#pragma unroll
    for (int t = 0; t < 8; ++t) {
      int r = w * 16 + t * 2 + ls;
      int sw = (t * 2 + ls) & 7;
      const u8* src = zb + (size_t)(m0 + r) * HH + ((ch & ~7) | ((ch & 7) ^ sw)) * 16;
      g2l16(src, AzB + w * 8192 + t * 1024);
    }
  }
  const int srow = lane >> 3;                   // 0..7
  const int schunk = ((lane & 7) ^ srow) * 16;  // XOR-swizzled source chunk
  auto stageW = [&](const u8* __restrict__ Wb, int kbyte) {
#pragma unroll
    for (int t = 0; t < 16; ++t)
      g2l16(Wb + (size_t)(w * 128 + t * 8 + srow) * HH + kbyte + schunk,
            WsB + w * 16384 + t * 1024);
  };
  stageW(W1b, 0);
  asm volatile("s_waitcnt vmcnt(0)" ::: "memory");
  __syncthreads();

  f32x4 acc[4][8];

  // ================= phase 1: h = ELU(z @ W1^T + b1) =================
#pragma unroll
  for (int mi = 0; mi < 4; ++mi)
#pragma unroll
    for (int ni = 0; ni < 8; ++ni) acc[mi][ni] = f32x4{0.f, 0.f, 0.f, 0.f};

#pragma unroll
  for (int k0 = 0; k0 < 4; ++k0) {
    i32x8 aF[4], bF[8];
#pragma unroll
    for (int mi = 0; mi < 4; ++mi) {
      int ar = mi * 16 + lo, sw = lo & 7;
      i32x4 p0 = *(const i32x4*)(AzB + ar * 512 + k0 * 128 + ((2 * quad) ^ sw) * 16);
      i32x4 p1 = *(const i32x4*)(AzB + ar * 512 + k0 * 128 + ((2 * quad + 1) ^ sw) * 16);
      aF[mi] = __builtin_shufflevector(p0, p1, 0, 1, 2, 3, 4, 5, 6, 7);
    }
#pragma unroll
    for (int ni = 0; ni < 8; ++ni) {
      int br = w * 128 + ni * 16 + lo, sw = br & 7;
      i32x4 p0 = *(const i32x4*)(WsB + br * 128 + ((2 * quad) ^ sw) * 16);
      i32x4 p1 = *(const i32x4*)(WsB + br * 128 + ((2 * quad + 1) ^ sw) * 16);
      bF[ni] = __builtin_shufflevector(p0, p1, 0, 1, 2, 3, 4, 5, 6, 7);
    }
    __syncthreads();  // all waves done reading Ws -> safe to overwrite
    if (k0 < 3) stageW(W1b, (k0 + 1) * 128);
    else        stageW(W2b, 0);          // prefetch W2 window 0 under MFMAs+epilogue
#pragma unroll
    for (int mi = 0; mi < 4; ++mi)
#pragma unroll
      for (int ni = 0; ni < 8; ++ni)
        acc[mi][ni] = __builtin_amdgcn_mfma_scale_f32_16x16x128_f8f6f4(
            aF[mi], bF[ni], acc[mi][ni], 0, 0, 0, 127, 0, 127);
    if (k0 < 3) __syncthreads();  // drains vmcnt -> next W tile resident
  }

  // h epilogue: bias + ELU + fp8, byte-scatter into swizzled Hs (W2(0) in flight)
  {
    float b1v[8];
#pragma unroll
    for (int ni = 0; ni < 8; ++ni) b1v[ni] = b1[w * 128 + ni * 16 + lo];
#pragma unroll
    for (int mi = 0; mi < 4; ++mi)
#pragma unroll
      for (int r = 0; r < 4; ++r) {
        int row = mi * 16 + quad * 4 + r;
        int rsw = row & 7;
#pragma unroll
        for (int ni = 0; ni < 8; ++ni) {
          float v = acc[mi][ni][r] + b1v[ni];
          if (v < 0.f) v = __expf(v) - 1.f;  // ELU
          int ch = w * 8 + ni;               // col>>4
          HsB[row * 512 + (((ch & 7) ^ rsw) | (ch & ~7)) * 16 + lo] = (char)(u8)f2fp8(v);
        }
      }
  }
  __syncthreads();  // Hs visible + W2(0) resident (barrier drains vmcnt+lgkm)

  // ================= phase 2: zp = h @ W2^T + b2 (kept in regs) =================
#pragma unroll
  for (int mi = 0; mi < 4; ++mi)
#pragma unroll
    for (int ni = 0; ni < 8; ++ni) acc[mi][ni] = f32x4{0.f, 0.f, 0.f, 0.f};

#pragma unroll
  for (int k0 = 0; k0 < 4; ++k0) {
    i32x8 aF[4], bF[8];
#pragma unroll
    for (int mi = 0; mi < 4; ++mi) {
      int ar = mi * 16 + lo, sw = lo & 7;
      i32x4 p0 = *(const i32x4*)(HsB + ar * 512 + k0 * 128 + ((2 * quad) ^ sw) * 16);
      i32x4 p1 = *(const i32x4*)(HsB + ar * 512 + k0 * 128 + ((2 * quad + 1) ^ sw) * 16);
      aF[mi] = __builtin_shufflevector(p0, p1, 0, 1, 2, 3, 4, 5, 6, 7);
    }
#pragma unroll
    for (int ni = 0; ni < 8; ++ni) {
      int br = w * 128 + ni * 16 + lo, sw = br & 7;
      i32x4 p0 = *(const i32x4*)(WsB + br * 128 + ((2 * quad) ^ sw) * 16);
      i32x4 p1 = *(const i32x4*)(WsB + br * 128 + ((2 * quad + 1) ^ sw) * 16);
      bF[ni] = __builtin_shufflevector(p0, p1, 0, 1, 2, 3, 4, 5, 6, 7);
    }
    if (k0 < 3) {
      __syncthreads();
      stageW(W2b, (k0 + 1) * 128);
    }
#pragma unroll
    for (int mi = 0; mi < 4; ++mi)
#pragma unroll
      for (int ni = 0; ni < 8; ++ni)
        acc[mi][ni] = __builtin_amdgcn_mfma_scale_f32_16x16x128_f8f6f4(
            aF[mi], bF[ni], acc[mi][ni], 0, 0, 0, 127, 0, 127);
    if (k0 < 3) __syncthreads();
  }

  // ---- bias + row sum-of-squares (in-register) ----
  float ssq[4][4] = {};
  {
    float b2v[8];
#pragma unroll
    for (int ni = 0; ni < 8; ++ni) b2v[ni] = b2[w * 128 + ni * 16 + lo];
#pragma unroll
    for (int mi = 0; mi < 4; ++mi)
#pragma unroll
      for (int ni = 0; ni < 8; ++ni)
#pragma unroll
        for (int r = 0; r < 4; ++r) {
          float v = acc[mi][ni][r] + b2v[ni];
          acc[mi][ni][r] = v;
          ssq[mi][r] += v * v;
        }
  }
#pragma unroll
  for (int d = 1; d < 16; d <<= 1)
#pragma unroll
    for (int mi = 0; mi < 4; ++mi)
#pragma unroll
      for (int r = 0; r < 4; ++r) ssq[mi][r] += __shfl_xor(ssq[mi][r], d, 64);
  if (lo == 0) {
#pragma unroll
    for (int mi = 0; mi < 4; ++mi)
#pragma unroll
      for (int r = 0; r < 4; ++r) ssqL[w][mi * 16 + quad * 4 + r] = ssq[mi][r];
  }
  __syncthreads();
  if (tid < 64)
    invL[tid] = nscale * rsqrtf(ssqL[0][tid] + ssqL[1][tid] + ssqL[2][tid] + ssqL[3][tid]);
  __syncthreads();

  // ---- zn = fp8(zp * inv) via LDS staging (Az region, linear) ----
#pragma unroll
  for (int mi = 0; mi < 4; ++mi)
#pragma unroll
    for (int r = 0; r < 4; ++r) {
      int row = mi * 16 + quad * 4 + r;
      float inv = invL[row];
#pragma unroll
      for (int ni = 0; ni < 8; ++ni)
        AzB[row * 512 + w * 128 + ni * 16 + lo] = (char)(u8)f2fp8(acc[mi][ni][r] * inv);
    }
  __syncthreads();
  {
    int row = tid >> 2, seg = tid & 3;
#pragma unroll
    for (int i = 0; i < 8; ++i) {
      i32x4 v = *(const i32x4*)(AzB + row * 512 + seg * 128 + i * 16);
      *(i32x4*)(zn + (size_t)(m0 + row) * 512 + seg * 128 + i * 16) = v;
    }
  }
}

// ---------------- similarity GEMM (MX-fp8, BK=128, LDS-staged) + reductions ----------------
__global__ __launch_bounds__(256)
void sim_kernel(const u8* __restrict__ Az, const u8* __restrict__ Bz,
                const u32* __restrict__ Pbits,
                float* __restrict__ rowpart, float* __restrict__ posrowpart,
                float* __restrict__ colpart, float* __restrict__ poscolpart) {
  __shared__ __align__(16) u8 As[128 * 128];   // 16 KB
  __shared__ __align__(16) u8 Bs[128 * 128];   // 16 KB
  __shared__ u32 PBi[128 * 4];
  __shared__ u32 PBj[128 * 4];
  const int tid = threadIdx.x;
  const int lane = tid & 63, w = tid >> 6;
  const int lo = lane & 15, quad = lane >> 4;
  const int wy = w >> 1, wx = w & 1;

  const int bid = blockIdx.x + (int)gridDim.x * blockIdx.y;
  const int xcd = bid & 7, s = bid >> 3;
  const int by = xcd * 8 + (s >> 6);
  const int bx = s & 63;
  const int i0 = by * 128, j0 = bx * 128;

  // prefetch pos bits into registers; they land during the K-loop
  const int il = tid >> 1, w2 = (tid & 1) * 2;
  const u32* PiSrc = Pbits + (size_t)(i0 + il) * NW + (j0 >> 5) + w2;
  const u32* PjSrc = Pbits + (size_t)(j0 + il) * NW + (i0 >> 5) + w2;
  u32 pa0 = PiSrc[0], pa1 = PiSrc[1], pb0 = PjSrc[0], pb1 = PjSrc[1];

  const int srow = lane >> 3;                   // 0..7
  const int schunk = ((lane & 7) ^ srow) * 16;  // XOR-swizzled source chunk
  char* AsB = (char*)As; char* BsB = (char*)Bs;
  f32x4 acc[4][4] = {};

  for (int k0 = 0; k0 < HH; k0 += 128) {
    const u8* ga = Az + (size_t)(i0 + w * 32 + srow) * HH + k0 + schunk;
    const u8* gb = Bz + (size_t)(j0 + w * 32 + srow) * HH + k0 + schunk;
#pragma unroll
    for (int t = 0; t < 4; ++t) {
      g2l16(ga + (size_t)(t * 8) * HH, AsB + w * 4096 + t * 1024);
      g2l16(gb + (size_t)(t * 8) * HH, BsB + w * 4096 + t * 1024);
    }
    asm volatile("s_waitcnt vmcnt(0)" ::: "memory");
    __syncthreads();
    i32x8 aF[4], bF[4];
#pragma unroll
    for (int mi = 0; mi < 4; ++mi) {
      int ar = wy * 64 + mi * 16 + lo;
      int sw = ar & 7;
      i32x4 p0 = *(const i32x4*)(AsB + ar * 128 + ((2 * quad) ^ sw) * 16);
      i32x4 p1 = *(const i32x4*)(AsB + ar * 128 + ((2 * quad + 1) ^ sw) * 16);
      aF[mi] = __builtin_shufflevector(p0, p1, 0, 1, 2, 3, 4, 5, 6, 7);
    }
#pragma unroll
    for (int ni = 0; ni < 4; ++ni) {
      int br = wx * 64 + ni * 16 + lo;
      int sw = br & 7;
      i32x4 p0 = *(const i32x4*)(BsB + br * 128 + ((2 * quad) ^ sw) * 16);
      i32x4 p1 = *(const i32x4*)(BsB + br * 128 + ((2 * quad + 1) ^ sw) * 16);
      bF[ni] = __builtin_shufflevector(p0, p1, 0, 1, 2, 3, 4, 5, 6, 7);
    }
#pragma unroll
    for (int mi = 0; mi < 4; ++mi)
#pragma unroll
      for (int ni = 0; ni < 4; ++ni)
        acc[mi][ni] = __builtin_amdgcn_mfma_scale_f32_16x16x128_f8f6f4(
            aF[mi], bF[ni], acc[mi][ni], 0, 0, 0, 127, 0, 127);  // e8m0 127 = 1.0
    __syncthreads();
  }

  // store prefetched pos bits to LDS
  PBi[il * 4 + w2] = pa0; PBi[il * 4 + w2 + 1] = pa1;
  PBj[il * 4 + w2] = pb0; PBj[il * 4 + w2 + 1] = pb1;

  // e = exp(cos/tau)
#pragma unroll
  for (int mi = 0; mi < 4; ++mi)
#pragma unroll
    for (int ni = 0; ni < 4; ++ni)
#pragma unroll
      for (int r = 0; r < 4; ++r)
        acc[mi][ni][r] = __expf(acc[mi][ni][r]);

  __syncthreads();

  const int rowb = wy * 64 + quad * 4;
  const int colb = wx * 64 + lo;

  // row reductions -> slot (bx*2 + wx)
#pragma unroll
  for (int mi = 0; mi < 4; ++mi) {
    int rl = rowb + mi * 16;
    float rs[4], pr[4];
#pragma unroll
    for (int r = 0; r < 4; ++r) {
      u32 W0 = PBi[(rl + r) * 4 + wx * 2];
      u32 W1 = PBi[(rl + r) * 4 + wx * 2 + 1];
      float e0 = acc[mi][0][r], e1 = acc[mi][1][r];
      float e2 = acc[mi][2][r], e3 = acc[mi][3][r];
      rs[r] = (e0 + e1) + (e2 + e3);
      pr[r] = (((W0 >> lo) & 1u) ? e0 : 0.f) + (((W0 >> (16 + lo)) & 1u) ? e1 : 0.f) +
              (((W1 >> lo) & 1u) ? e2 : 0.f) + (((W1 >> (16 + lo)) & 1u) ? e3 : 0.f);
    }
#pragma unroll
    for (int d = 1; d < 16; d <<= 1) {
#pragma unroll
      for (int r = 0; r < 4; ++r) {
        rs[r] += __shfl_xor(rs[r], d, 64);
        pr[r] += __shfl_xor(pr[r], d, 64);
      }
    }
    if (lo == 0) {
      float* rp = rowpart + (size_t)(bx * 2 + wx) * NN;
      float* pp = posrowpart + (size_t)(bx * 2 + wx) * NN;
#pragma unroll
      for (int r = 0; r < 4; ++r) {
        rp[i0 + rl + r] = rs[r];
        pp[i0 + rl + r] = pr[r];
      }
    }
  }

  // col reductions -> slot (by*2 + wy)
#pragma unroll
  for (int ni = 0; ni < 4; ++ni) {
    int cl = colb + ni * 16;
    u32 W0 = PBj[cl * 4 + wy * 2];
    u32 W1 = PBj[cl * 4 + wy * 2 + 1];
    float cs = 0.f, pc = 0.f;
#pragma unroll
    for (int mi = 0; mi < 4; ++mi) {
      u32 W = (mi < 2) ? W0 : W1;
      int sh = (mi & 1) * 16 + quad * 4;
#pragma unroll
      for (int r = 0; r < 4; ++r) {
        float e = acc[mi][ni][r];
        cs += e;
        pc += ((W >> (sh + r)) & 1u) ? e : 0.f;
      }
    }
    cs += __shfl_xor(cs, 16, 64); cs += __shfl_xor(cs, 32, 64);
    pc += __shfl_xor(pc, 16, 64); pc += __shfl_xor(pc, 32, 64);
    if (quad == 0) {
      colpart[(size_t)(by * 2 + wy) * NN + j0 + cl] = cs;
      poscolpart[(size_t)(by * 2 + wy) * NN + j0 + cl] = pc;
    }
  }
}

// ---------------- stage-1 reduce ----------------
__global__ __launch_bounds__(256)
void reduce1_kernel(const float* __restrict__ rowpart, const float* __restrict__ posrowpart,
                    const float* __restrict__ colpart, const float* __restrict__ poscolpart,
                    float* __restrict__ red) {
  int t = threadIdx.x;
  int i = blockIdx.x * 128 + (t >> 1);
  int half = t & 1;
  float rs = 0.f, pr = 0.f, cs = 0.f, pc = 0.f;
  for (int s = half * 64; s < half * 64 + 64; ++s) {
    rs += rowpart[(size_t)s * NN + i];
    pr += posrowpart[(size_t)s * NN + i];
    cs += colpart[(size_t)s * NN + i];
    pc += poscolpart[(size_t)s * NN + i];
  }
  rs += __shfl_xor(rs, 1, 64); pr += __shfl_xor(pr, 1, 64);
  cs += __shfl_xor(cs, 1, 64); pc += __shfl_xor(pc, 1, 64);
  float term = (half == 0) ? (__logf(pr / (rs + EPSF)) + __logf(pc / (cs + EPSF))) : 0.f;
#pragma unroll
  for (int d = 2; d < 64; d <<= 1) term += __shfl_xor(term, d, 64);
  __shared__ float rsh[4];
  if ((t & 63) == 0) rsh[t >> 6] = term;
  __syncthreads();
  if (t == 0) red[blockIdx.x] = rsh[0] + rsh[1] + rsh[2] + rsh[3];
}

__global__ void reduce2_kernel(const float* __restrict__ red, float* __restrict__ out) {
  float s = red[threadIdx.x];  // 64 threads
#pragma unroll
  for (int d = 1; d < 64; d <<= 1) s += __shfl_xor(s, d, 64);
  if (threadIdx.x == 0) out[0] = -0.5f * s / (float)NN;
}

extern "C" void kernel_launch(void* const* d_in, const int* in_sizes, int n_in,
                              void* d_out, int out_size, void* d_ws, size_t ws_size,
                              hipStream_t stream) {
  const float* z_mp = (const float*)d_in[0];
  const float* z_sc = (const float*)d_in[1];
  const int* pos = (const int*)d_in[2];
  const float* W1 = (const float*)d_in[3];
  const float* b1 = (const float*)d_in[4];
  const float* W2 = (const float*)d_in[5];
  const float* b2 = (const float*)d_in[6];
  float* out = (float*)d_out;

  char* ws = (char*)d_ws;
  u32* Pbits = (u32*)(ws);                    // [0, 8MB)
  u8* zbA = (u8*)(ws + 8388608);              // 4 MB (z fp8; overwritten in-place by zn)
  u8* zbB = (u8*)(ws + 16777216);             // 4 MB
  u8* W1b = (u8*)(ws + 25165824);             // 256 KB
  u8* W2b = (u8*)(ws + 25690112);             // 256 KB
  float* rowpart    = (float*)(ws + 26214400);  // 4 MB each
  float* posrowpart = (float*)(ws + 30408704);
  float* colpart    = (float*)(ws + 34603008);
  float* poscolpart = (float*)(ws + 38797312);
  float* red64 = (float*)(ws + 76546048);

  prep_kernel<<<12544, 256, 0, stream>>>(pos, Pbits, z_mp, zbA, z_sc, zbB, W1, W1b, W2, W2b);

  // fused z -> h -> zp -> zn; writes zn in place over zb (row-local, safe)
  proj_fused<<<256, 256, 0, stream>>>(zbA, zbB, W1b, b1, W2b, b2, zbA, zbB);

  dim3 gs(64, 64);
  sim_kernel<<<gs, 256, 0, stream>>>(zbA, zbB, Pbits, rowpart, posrowpart, colpart, poscolpart);
  reduce1_kernel<<<64, 256, 0, stream>>>(rowpart, posrowpart, colpart, poscolpart, red64);
  reduce2_kernel<<<1, 64, 0, stream>>>(red64, out);
}